// Round 3
// baseline (263.283 us; speedup 1.0000x reference)
//
#include <hip/hip_runtime.h>

// LatticeCrf log_prob on MI355X — MFMA chunked linear-space scan, v3.
// P_c = M_c^T via P <- E_t^T * P, two v_mfma_f32_32x32x16_bf16 per step.
// sigma (contraction-index permutation) folded into A-operand load offsets so
// the fp32 accumulator (C-layout) feeds the B operand directly after bf16 pack.
// v3: compile-time L, 2-step-deep dual-bank register prefetch (32 loads in
// flight/wave), CC=64 (4 waves/SIMD), hoisted zero-C vector.
#define BB 64
#define TT 512
#define VV 32
#define LOG2E 1.4426950408889634f
#define LN2f  0.6931471805599453f
#define SHIFT 6.0f

typedef __bf16 bf16x8 __attribute__((ext_vector_type(8)));
typedef float  f32x16 __attribute__((ext_vector_type(16)));

union Frag { unsigned int u[4]; bf16x8 v; };

// round-half-up fp32->bf16 (inputs positive finite), pack two into one dword
__device__ __forceinline__ unsigned int pack_bf16(float lo, float hi) {
    unsigned int a = __float_as_uint(lo) + 0x8000u;
    unsigned int b = __float_as_uint(hi) + 0x8000u;
    return __builtin_amdgcn_perm(b, a, 0x07060302u); // [a.b2,a.b3,b.b2,b.b3]
}

template <int L>
__global__ __launch_bounds__(256) void crf_chunk_kernel(
    const float* __restrict__ scores,
    const float* __restrict__ w_tx,
    const float* __restrict__ w_dur,
    float* __restrict__ ws_M)
{
    constexpr int CC = TT / L;
    const int lane  = threadIdx.x & 63;
    const int wid   = threadIdx.x >> 6;
    const int chunk = blockIdx.x * 4 + wid;
    const int m = lane & 31;           // output column of P (row of M)
    const int h = lane >> 5;

    // sigma(j,h) = (j&3) + 8*(j>>2) + 4h ; float offset = sigma*32 + m
    const int base = h * 128 + m;

    float w2[16];
#pragma unroll
    for (int j = 0; j < 8; ++j) {
        const int off = base + (j & 3) * 32 + (j >> 2) * 256;
        w2[j]     = (w_tx[off]       + w_dur[off])       * LOG2E - SHIFT;
        w2[j + 8] = (w_tx[off + 512] + w_dur[off + 512]) * LOG2E - SHIFT;
    }

    const int b = chunk / CC, c = chunk - b * CC;
    const float* sc = scores + ((size_t)(b * TT + c * L)) * 1024 + base;

    // dual-bank prefetch: bank t&1 holds step t
    float s[2][16];
#pragma unroll
    for (int j = 0; j < 8; ++j) {
        const int off = (j & 3) * 32 + (j >> 2) * 256;
        s[0][j]     = sc[off];
        s[0][j + 8] = sc[off + 512];
    }
    if (L > 1) {
#pragma unroll
        for (int j = 0; j < 8; ++j) {
            const int off = 1024 + (j & 3) * 32 + (j >> 2) * 256;
            s[1][j]     = sc[off];
            s[1][j + 8] = sc[off + 512];
        }
    }

    // acc = P in C-layout, init identity: reg r holds P[mr][m]
    f32x16 acc;
#pragma unroll
    for (int r = 0; r < 16; ++r) {
        const int mr = (r & 3) + 8 * (r >> 2) + 4 * h;
        acc[r] = (mr == m) ? 1.0f : 0.0f;
    }

    f32x16 z;   // loop-invariant zero C operand
#pragma unroll
    for (int r = 0; r < 16; ++r) z[r] = 0.0f;

#pragma unroll
    for (int t = 0; t < L; ++t) {
        const int bk = t & 1;

        float e[16];
#pragma unroll
        for (int j = 0; j < 16; ++j)
            e[j] = __builtin_amdgcn_exp2f(__builtin_fmaf(s[bk][j], LOG2E, w2[j]));

        // refill this bank with step t+2 (32 loads in flight across banks)
        if (t + 2 < L) {
            const float* sn = sc + (size_t)(t + 2) * 1024;
#pragma unroll
            for (int j = 0; j < 8; ++j) {
                const int off = (j & 3) * 32 + (j >> 2) * 256;
                s[bk][j]     = sn[off];
                s[bk][j + 8] = sn[off + 512];
            }
        }

        Frag a1, a2, b1, b2;
#pragma unroll
        for (int p = 0; p < 4; ++p) {
            a1.u[p] = pack_bf16(e[2 * p],       e[2 * p + 1]);
            a2.u[p] = pack_bf16(e[8 + 2 * p],   e[8 + 2 * p + 1]);
            b1.u[p] = pack_bf16(acc[2 * p],     acc[2 * p + 1]);
            b2.u[p] = pack_bf16(acc[8 + 2 * p], acc[8 + 2 * p + 1]);
        }

        f32x16 tmp = __builtin_amdgcn_mfma_f32_32x32x16_bf16(a1.v, b1.v, z,   0, 0, 0);
        acc        = __builtin_amdgcn_mfma_f32_32x32x16_bf16(a2.v, b2.v, tmp, 0, 0, 0);
    }

    // write P row-major: P[mr][m] -> ws[chunk*1024 + mr*32 + m]
    float* outP = ws_M + (size_t)chunk * 1024;
#pragma unroll
    for (int r = 0; r < 16; ++r) {
        const int mr = (r & 3) + 8 * (r >> 2) + 4 * h;
        outP[mr * 32 + m] = acc[r];
    }
}

__global__ __launch_bounds__(64) void crf_combine_kernel(
    const float* __restrict__ scores,
    const int*   __restrict__ targets,
    const float* __restrict__ w_tx,
    const float* __restrict__ w_init,
    const float* __restrict__ w_final,
    const float* __restrict__ w_dur,
    const float* __restrict__ ws_M,
    float* __restrict__ out,
    int CC)
{
    const int b    = blockIdx.x;
    const int lane = threadIdx.x;   // 0..63

    // ---- numerator ----
    const int* tg = targets + b * (TT + 1);
    float num = 0.f;
#pragma unroll
    for (int k = 0; k < TT / 64; ++k) {
        const int t  = lane + 64 * k;
        const int s_ = tg[t];
        const int d_ = tg[t + 1];
        const int wi = s_ * VV + d_;
        num += scores[(((size_t)b * TT + t) * VV + s_) * VV + d_] + w_tx[wi] + w_dur[wi];
    }
#pragma unroll
    for (int mS = 32; mS >= 1; mS >>= 1) num += __shfl_xor(num, mS, 64);

    // ---- denominator: a_new[j] = dot(P_c row j, a), renorm each chunk ----
    const int j = lane & 31;
    float a    = __builtin_amdgcn_exp2f(w_init[j] * LOG2E);
    float accl = 0.f;
    const float* Pb = ws_M + (size_t)b * CC * 1024;

    float4 rr[8];
#pragma unroll
    for (int q = 0; q < 8; ++q) rr[q] = *(const float4*)(Pb + j * 32 + 4 * q);

    for (int c = 0; c < CC; ++c) {
        float4 rn[8];
        if (c + 1 < CC) {
            const float* Pn = Pb + (size_t)(c + 1) * 1024 + j * 32;
#pragma unroll
            for (int q = 0; q < 8; ++q) rn[q] = *(const float4*)(Pn + 4 * q);
        }
        float an = 0.f;
#pragma unroll
        for (int i = 0; i < 32; ++i) {
            const float  ai = __shfl(a, i, 32);
            const float4 v  = rr[i >> 2];
            const float  pv = ((i & 3) == 0) ? v.x : ((i & 3) == 1) ? v.y
                             : ((i & 3) == 2) ? v.z : v.w;
            an = __builtin_fmaf(ai, pv, an);
        }
        float mx = an;
#pragma unroll
        for (int mS = 16; mS >= 1; mS >>= 1) mx = fmaxf(mx, __shfl_xor(mx, mS, 32));
        a = an / mx;
        accl += __builtin_amdgcn_logf(mx);   // log2
        if (c + 1 < CC) {
#pragma unroll
            for (int q = 0; q < 8; ++q) rr[q] = rn[q];
        }
    }

    float rf = a * __builtin_amdgcn_exp2f(w_final[j] * LOG2E);
    float ss = rf;
#pragma unroll
    for (int mS = 16; mS >= 1; mS >>= 1) ss += __shfl_xor(ss, mS, 32);
    const float denom_ln =
        (__builtin_amdgcn_logf(ss) + accl + SHIFT * (float)TT) * LN2f;

    if (lane == 0) {
        out[b] = num + w_init[tg[0]] + w_final[tg[TT]] - denom_ln;
    }
}

extern "C" void kernel_launch(void* const* d_in, const int* in_sizes, int n_in,
                              void* d_out, int out_size, void* d_ws, size_t ws_size,
                              hipStream_t stream) {
    const float* scores  = (const float*)d_in[0];
    const int*   targets = (const int*)d_in[1];
    const float* w_tx    = (const float*)d_in[2];
    const float* w_init  = (const float*)d_in[3];
    const float* w_final = (const float*)d_in[4];
    const float* w_dur   = (const float*)d_in[5];
    float*       out     = (float*)d_out;
    float*       ws_M    = (float*)d_ws;

    int CC;
    if (ws_size >= (size_t)BB * 64 * 4096) {          // 16 MiB
        CC = 64;
        crf_chunk_kernel<8><<<BB * CC / 4, 256, 0, stream>>>(scores, w_tx, w_dur, ws_M);
    } else if (ws_size >= (size_t)BB * 32 * 4096) {   // 8 MiB
        CC = 32;
        crf_chunk_kernel<16><<<BB * CC / 4, 256, 0, stream>>>(scores, w_tx, w_dur, ws_M);
    } else {                                          // 2 MiB
        CC = 8;
        crf_chunk_kernel<64><<<BB * CC / 4, 256, 0, stream>>>(scores, w_tx, w_dur, ws_M);
    }
    crf_combine_kernel<<<BB, 64, 0, stream>>>(scores, targets, w_tx, w_init,
                                              w_final, w_dur, ws_M, out, CC);
}

// Round 4
// 209.648 us; speedup vs baseline: 1.2558x; 1.2558x over previous
//
#include <hip/hip_runtime.h>

// LatticeCrf log_prob on MI355X — MFMA chunked linear-space scan, v4.
// P_c = M_c^T via P <- E_t^T * P, two v_mfma_f32_32x32x16_bf16 per step.
// sigma (contraction-index permutation) folded into A-operand addressing so the
// fp32 accumulator (C-layout) feeds the B operand directly after bf16 pack.
// v4: CC=64/L=8 (4 waves/SIMD), in-block tree combine of 4 chunk matrices via
// LDS-fed MFMA (combine kernel sees 16 matrices/b), w2 table in LDS, numerator
// fused into chunk kernel via atomicAdd.
#define BB 64
#define TT 512
#define VV 32
#define CC 64           // chunks per sequence
#define L  8            // steps per chunk
#define QPB 4           // chunks per block (tree-combined)
#define NMAT (CC/QPB)   // 16 combined matrices per b
#define PSTR 34         // LDS pad stride (even: b64-aligned, 2-way conflicts only)
#define LOG2E 1.4426950408889634f
#define LN2f  0.6931471805599453f
#define SHIFT 6.0f

typedef __bf16 bf16x8 __attribute__((ext_vector_type(8)));
typedef float  f32x16 __attribute__((ext_vector_type(16)));
union Frag { unsigned int u[4]; bf16x8 v; };

// round-half-up fp32->bf16 (inputs positive finite), pack two into one dword
__device__ __forceinline__ unsigned int pack_bf16(float lo, float hi) {
    unsigned int a = __float_as_uint(lo) + 0x8000u;
    unsigned int b = __float_as_uint(hi) + 0x8000u;
    return __builtin_amdgcn_perm(b, a, 0x07060302u); // [a.b2,a.b3,b.b2,b.b3]
}

// C-layout row for reg r / A-layout sigma for slot j: (x&3) + 8*(x>>2) + 4h
__device__ __forceinline__ int rowmap(int x, int h) {
    return (x & 3) + 8 * (x >> 2) + 4 * h;
}

// result = P_lds * accB   (A from LDS row-major stride PSTR, B = raw C-regs)
__device__ __forceinline__ f32x16 lds_mul(const float* P, int r, int h,
                                          const f32x16& accB) {
    Frag a1, a2, b1, b2;
#pragma unroll
    for (int p = 0; p < 4; ++p) {
        const int k1 = rowmap(2 * p, h);       // 0,2,8,10 (+4h)
        const int k2 = k1 + 16;
        const float2 x1 = *(const float2*)&P[r * PSTR + k1];
        const float2 x2 = *(const float2*)&P[r * PSTR + k2];
        a1.u[p] = pack_bf16(x1.x, x1.y);
        a2.u[p] = pack_bf16(x2.x, x2.y);
        b1.u[p] = pack_bf16(accB[2 * p],     accB[2 * p + 1]);
        b2.u[p] = pack_bf16(accB[8 + 2 * p], accB[8 + 2 * p + 1]);
    }
    f32x16 z;
#pragma unroll
    for (int i = 0; i < 16; ++i) z[i] = 0.f;
    f32x16 t = __builtin_amdgcn_mfma_f32_32x32x16_bf16(a1.v, b1.v, z, 0, 0, 0);
    return   __builtin_amdgcn_mfma_f32_32x32x16_bf16(a2.v, b2.v, t, 0, 0, 0);
}

__device__ __forceinline__ void lds_export(float* P, int m, int h,
                                           const f32x16& acc) {
#pragma unroll
    for (int r = 0; r < 16; ++r)
        P[rowmap(r, h) * PSTR + m] = acc[r];
}

__global__ __launch_bounds__(256, 4) void crf_chunk_fused(
    const float* __restrict__ scores,
    const int*   __restrict__ targets,
    const float* __restrict__ w_tx,
    const float* __restrict__ w_dur,
    float* __restrict__ ws_M,
    float* __restrict__ out)
{
    __shared__ float w2s[VV * VV];
    __shared__ float pbuf[2][VV * PSTR];

    const int tid  = threadIdx.x;
    const int lane = tid & 63;
    const int wid  = tid >> 6;
    const int m    = lane & 31;
    const int h    = lane >> 5;
    const int b    = blockIdx.x >> 4;
    const int q    = blockIdx.x & 15;
    const int c    = q * QPB + wid;

    // stage w2 = (w_tx + w_dur)*log2e - SHIFT into LDS (1024 entries)
    {
        const float4 wt = *(const float4*)(w_tx  + tid * 4);
        const float4 wd = *(const float4*)(w_dur + tid * 4);
        float4 r;
        r.x = (wt.x + wd.x) * LOG2E - SHIFT;
        r.y = (wt.y + wd.y) * LOG2E - SHIFT;
        r.z = (wt.z + wd.z) * LOG2E - SHIFT;
        r.w = (wt.w + wd.w) * LOG2E - SHIFT;
        *(float4*)&w2s[tid * 4] = r;
    }
    __syncthreads();

    float w2[16];
#pragma unroll
    for (int j = 0; j < 16; ++j)
        w2[j] = w2s[rowmap(j, h) * VV + m];

    const float* sc = scores + ((size_t)b * TT + (size_t)c * L) * 1024 + m;

    // dual-bank register prefetch (32 loads in flight per wave)
    float s[2][16];
#pragma unroll
    for (int j = 0; j < 16; ++j) {
        const int off = rowmap(j, h) * VV;
        s[0][j] = sc[off];
        s[1][j] = sc[1024 + off];
    }

    f32x16 acc;
#pragma unroll
    for (int r = 0; r < 16; ++r)
        acc[r] = (rowmap(r, h) == m) ? 1.0f : 0.0f;
    f32x16 z;
#pragma unroll
    for (int i = 0; i < 16; ++i) z[i] = 0.f;

#pragma unroll
    for (int t = 0; t < L; ++t) {
        const int bk = t & 1;
        float e[16];
#pragma unroll
        for (int j = 0; j < 16; ++j)
            e[j] = __builtin_amdgcn_exp2f(__builtin_fmaf(s[bk][j], LOG2E, w2[j]));

        if (t + 2 < L) {
            const float* sn = sc + (size_t)(t + 2) * 1024;
#pragma unroll
            for (int j = 0; j < 16; ++j)
                s[bk][j] = sn[rowmap(j, h) * VV];
        }

        Frag a1, a2, b1, b2;
#pragma unroll
        for (int p = 0; p < 4; ++p) {
            a1.u[p] = pack_bf16(e[2 * p],       e[2 * p + 1]);
            a2.u[p] = pack_bf16(e[8 + 2 * p],   e[8 + 2 * p + 1]);
            b1.u[p] = pack_bf16(acc[2 * p],     acc[2 * p + 1]);
            b2.u[p] = pack_bf16(acc[8 + 2 * p], acc[8 + 2 * p + 1]);
        }
        f32x16 tmp = __builtin_amdgcn_mfma_f32_32x32x16_bf16(a1.v, b1.v, z,   0, 0, 0);
        acc        = __builtin_amdgcn_mfma_f32_32x32x16_bf16(a2.v, b2.v, tmp, 0, 0, 0);
    }

    // ---- in-block tree combine: P_total = (P3*P2)*(P1*P0) ----
    if (wid == 1) lds_export(pbuf[0], m, h, acc);
    if (wid == 3) lds_export(pbuf[1], m, h, acc);
    __syncthreads();
    if (wid == 0) acc = lds_mul(pbuf[0], m, h, acc);   // P1*P0
    if (wid == 2) acc = lds_mul(pbuf[1], m, h, acc);   // P3*P2
    if (wid == 3 && lane < 32) {
        // numerator partial for steps [q*32, q*32+32) — scores L2-hot here
        const int  t  = q * 32 + lane;
        const int* tg = targets + b * (TT + 1);
        const int  s_ = tg[t], d_ = tg[t + 1];
        const int  wi = s_ * VV + d_;
        float v = scores[((size_t)b * TT + t) * 1024 + wi] + w_tx[wi] + w_dur[wi];
#pragma unroll
        for (int mS = 16; mS >= 1; mS >>= 1) v += __shfl_xor(v, mS, 32);
        if (lane == 0) atomicAdd(out + b, v);
    }
    __syncthreads();
    if (wid == 2) lds_export(pbuf[0], m, h, acc);
    __syncthreads();
    if (wid == 0) {
        acc = lds_mul(pbuf[0], m, h, acc);             // (P3P2)*(P1P0)
        float* outP = ws_M + ((size_t)b * NMAT + q) * 1024;
#pragma unroll
        for (int r = 0; r < 16; ++r)
            outP[rowmap(r, h) * VV + m] = acc[r];
    }
}

__global__ __launch_bounds__(64) void crf_combine_kernel(
    const int*   __restrict__ targets,
    const float* __restrict__ w_init,
    const float* __restrict__ w_final,
    const float* __restrict__ ws_M,
    float* __restrict__ out)
{
    const int b    = blockIdx.x;
    const int lane = threadIdx.x;
    const int j    = lane & 31;

    float a    = __builtin_amdgcn_exp2f(w_init[j] * LOG2E);
    float accl = 0.f;
    const float* Pb = ws_M + (size_t)b * NMAT * 1024;

    float4 rr[8], rn[8];
#pragma unroll
    for (int qd = 0; qd < 8; ++qd) rr[qd] = *(const float4*)(Pb + j * VV + 4 * qd);

    for (int cI = 0; cI < NMAT; ++cI) {
        if (cI + 1 < NMAT) {
            const float* Pn = Pb + (size_t)(cI + 1) * 1024 + j * VV;
#pragma unroll
            for (int qd = 0; qd < 8; ++qd) rn[qd] = *(const float4*)(Pn + 4 * qd);
        }
        float an = 0.f;
#pragma unroll
        for (int i = 0; i < 32; ++i) {
            const float  ai = __shfl(a, i, 32);
            const float4 v  = rr[i >> 2];
            const float  pv = ((i & 3) == 0) ? v.x : ((i & 3) == 1) ? v.y
                             : ((i & 3) == 2) ? v.z : v.w;
            an = __builtin_fmaf(ai, pv, an);
        }
        float mx = an;
#pragma unroll
        for (int mS = 16; mS >= 1; mS >>= 1) mx = fmaxf(mx, __shfl_xor(mx, mS, 32));
        a = an / mx;
        accl += __builtin_amdgcn_logf(mx);   // log2
#pragma unroll
        for (int qd = 0; qd < 8; ++qd) rr[qd] = rn[qd];
    }

    float ss = a * __builtin_amdgcn_exp2f(w_final[j] * LOG2E);
#pragma unroll
    for (int mS = 16; mS >= 1; mS >>= 1) ss += __shfl_xor(ss, mS, 32);
    const float denom_ln =
        (__builtin_amdgcn_logf(ss) + accl + SHIFT * (float)TT) * LN2f;

    if (lane == 0) {
        const int* tg = targets + b * (TT + 1);
        atomicAdd(out + b, w_init[tg[0]] + w_final[tg[TT]] - denom_ln);
    }
}

extern "C" void kernel_launch(void* const* d_in, const int* in_sizes, int n_in,
                              void* d_out, int out_size, void* d_ws, size_t ws_size,
                              hipStream_t stream) {
    const float* scores  = (const float*)d_in[0];
    const int*   targets = (const int*)d_in[1];
    const float* w_tx    = (const float*)d_in[2];
    const float* w_init  = (const float*)d_in[3];
    const float* w_final = (const float*)d_in[4];
    const float* w_dur   = (const float*)d_in[5];
    float*       out     = (float*)d_out;
    float*       ws_M    = (float*)d_ws;   // BB*NMAT*4KB = 4 MiB

    hipMemsetAsync(out, 0, BB * sizeof(float), stream);
    crf_chunk_fused<<<BB * NMAT, 256, 0, stream>>>(scores, targets, w_tx, w_dur,
                                                   ws_M, out);
    crf_combine_kernel<<<BB, 64, 0, stream>>>(targets, w_init, w_final, ws_M, out);
}